// Round 3
// baseline (285.415 us; speedup 1.0000x reference)
//
#include <hip/hip_runtime.h>
#include <hip/hip_bf16.h>
#include <cstdint>

// Problem constants (B=16, N=4096, D_IN=D_OUT=64)
#define NB   16
#define NN   4096
#define ND   64
#define NJ   1024   // NB*ND columns of the big GEMM

typedef __attribute__((ext_vector_type(8))) short  short8;  // 8 bf16 = 4 VGPRs
typedef __attribute__((ext_vector_type(4))) float  f32x4;

__device__ __forceinline__ unsigned short f2bf(float f) {
  union { float f; unsigned int u; } v; v.f = f;
  unsigned int u = v.u;
  unsigned int r = u + 0x7FFFu + ((u >> 16) & 1u);  // round-to-nearest-even
  return (unsigned short)(r >> 16);
}

// ---------------- K1: A fp32 -> bf16 (vectorized) + zero d_out (replaces memset) ------
__global__ void k_convert(const float* __restrict__ A, unsigned short* __restrict__ Ab,
                          float* __restrict__ outz) {
  int idx = blockIdx.x * 256 + threadIdx.x;          // 2,097,152 threads exactly
  const float4* p = (const float4*)A + (size_t)idx * 2;
  float4 a = p[0], b = p[1];
  unsigned int w0 = (unsigned int)f2bf(a.x) | ((unsigned int)f2bf(a.y) << 16);
  unsigned int w1 = (unsigned int)f2bf(a.z) | ((unsigned int)f2bf(a.w) << 16);
  unsigned int w2 = (unsigned int)f2bf(b.x) | ((unsigned int)f2bf(b.y) << 16);
  unsigned int w3 = (unsigned int)f2bf(b.z) | ((unsigned int)f2bf(b.w) << 16);
  uint4 o; o.x = w0; o.y = w1; o.z = w2; o.w = w3;
  ((uint4*)Ab)[idx] = o;                             // 16B store
  if (idx < (NB * NN * ND / 4))                      // 1,048,576 float4s = 16 MiB
    ((float4*)outz)[idx] = (float4){0.f, 0.f, 0.f, 0.f};  // split-K accumulator base
}

// ---------------- K2: Yt[b*64+e][m] = sum_d Z[b][m][d]*W[d][e], fp32 math -> bf16 ----
__global__ void k_zw(const float* __restrict__ Z, const float* __restrict__ W,
                     unsigned short* __restrict__ Yt) {
  int lane = threadIdx.x & 63;
  int e0 = __builtin_amdgcn_readfirstlane((threadIdx.x >> 6) << 4);  // wave-uniform -> s_load W
  int b  = blockIdx.x >> 6;          // [0,16)
  int m0 = (blockIdx.x & 63) << 6;   // [0,4096) step 64
  int m  = m0 + lane;
  const float* zr = Z + ((size_t)b * NN + m) * ND;
  float z[64];
#pragma unroll
  for (int g = 0; g < 16; ++g) *(float4*)&z[g * 4] = ((const float4*)zr)[g];
  float acc[16];
#pragma unroll
  for (int i = 0; i < 16; ++i) acc[i] = 0.f;
#pragma unroll
  for (int d = 0; d < 64; ++d) {
    float zd = z[d];
#pragma unroll
    for (int i = 0; i < 16; ++i) acc[i] += zd * W[d * 64 + e0 + i];  // uniform addr -> SMEM
  }
#pragma unroll
  for (int i = 0; i < 16; ++i)
    Yt[(size_t)(b * 64 + e0 + i) * NN + m] = f2bf(acc[i]);
}

// ---------------- K3: Out += Ab[4096x4096] @ Y (Yt is [j][k], k-contiguous) -----------
// BARRIER-FREE: no LDS. Each wave loads its MFMA fragments directly from global:
//   A frag (16x16x32): lane holds A[m = mrow0+wrow+i*16+l15][k = k0+quad*8 .. +8]
//     -> addr = (row)*4096 + k; 16 rows x 64B contiguous segments per instr.
//   B frag: lane holds B[k][n] = Yt[j = jcol0+wcol+i*16+l15][k] -> identical pattern.
// No __syncthreads -> compiler pipelines loads across k-steps with vmcnt(N) waits
// (the AITER pattern the 2-barrier structure cannot express). L1/L2 serve the 2x reuse
// the LDS used to provide (wave pairs read identical fragments near-simultaneously).
__launch_bounds__(256, 4)  // 4 blocks/CU = 16 waves; reg target <=128/wave
__global__ void k_gemm(const unsigned short* __restrict__ Ab,
                       const unsigned short* __restrict__ Yt,
                       float* __restrict__ out) {
  int tid = threadIdx.x;
  int w = tid >> 6, lane = tid & 63;
  int quad = lane >> 4, l15 = lane & 15;

  // XCD swizzle: bx%8 = XCD. t order: j fastest (8 j-blocks share one A strip in L2),
  // then kc, then m. grid = 8 XCD * 128.
  int x = blockIdx.x & 7;
  int t = blockIdx.x >> 3;           // [0,128)
  int j_blk = t & 7;
  int kc    = (t >> 3) & 3;
  int m_blk = x * 4 + (t >> 5);
  int mrow0 = m_blk * 128;
  int jcol0 = j_blk * 128;
  int kbase = kc * 1024;             // this block's 1024-wide K chunk

  int wrow = (w >> 1) * 64, wcol = (w & 1) * 64;

  // Per-lane fragment base pointers (advance by 32 shorts per BK=32 step)
  const unsigned short* a = Ab + (size_t)(mrow0 + wrow + l15) * 4096 + kbase + quad * 8;
  const unsigned short* b = Yt + (size_t)(jcol0 + wcol + l15) * 4096 + kbase + quad * 8;

  f32x4 acc[4][4];
#pragma unroll
  for (int i = 0; i < 4; ++i)
#pragma unroll
    for (int j = 0; j < 4; ++j) acc[i][j] = (f32x4){0.f, 0.f, 0.f, 0.f};

#pragma unroll 2
  for (int kt = 0; kt < 32; ++kt) {  // 32 steps of BK=32 over this block's K=1024
    short8 af[4], bf[4];
#pragma unroll
    for (int i = 0; i < 4; ++i) af[i] = *(const short8*)(a + (size_t)i * 65536);  // i*16 rows
#pragma unroll
    for (int i = 0; i < 4; ++i) bf[i] = *(const short8*)(b + (size_t)i * 65536);
#pragma unroll
    for (int i = 0; i < 4; ++i)
#pragma unroll
      for (int j = 0; j < 4; ++j)
        acc[i][j] = __builtin_amdgcn_mfma_f32_16x16x32_bf16(af[i], bf[j], acc[i][j], 0, 0, 0);
    a += 32;
    b += 32;
  }

  // Epilogue: C/D layout col=l15, row=quad*4+reg (m89/m91-verified).
  // out[b][n][e] flat = ((j>>6)*4096 + n)*64 + (j&63); split-K -> atomicAdd (out pre-zeroed).
#pragma unroll
  for (int i = 0; i < 4; ++i) {
    int r0 = mrow0 + wrow + i * 16 + quad * 4;
#pragma unroll
    for (int j = 0; j < 4; ++j) {
      int jc = jcol0 + wcol + j * 16 + l15;
      int bidx = jc >> 6, e = jc & 63;
      float* op = out + ((size_t)bidx * NN + r0) * 64 + e;
#pragma unroll
      for (int rg = 0; rg < 4; ++rg)
        atomicAdd(op + (size_t)rg * 64, acc[i][j][rg]);
    }
  }
}

extern "C" void kernel_launch(void* const* d_in, const int* in_sizes, int n_in,
                              void* d_out, int out_size, void* d_ws, size_t ws_size,
                              hipStream_t stream) {
  const float* Z = (const float*)d_in[0];   // [16][4096][64] fp32
  const float* A = (const float*)d_in[1];   // [4096][4096] fp32
  const float* W = (const float*)d_in[2];   // [64][64] fp32
  float* out = (float*)d_out;               // [16][4096][64] fp32

  unsigned short* Ab = (unsigned short*)d_ws;                                     // 32 MiB bf16 A
  unsigned short* Yt = (unsigned short*)((char*)d_ws + (size_t)32 * 1024 * 1024); // 8 MiB bf16 Y^T

  k_convert<<<8192, 256, 0, stream>>>(A, Ab, out);   // also zeroes out (split-K base)
  k_zw<<<1024, 256, 0, stream>>>(Z, W, Yt);
  k_gemm<<<1024, 256, 0, stream>>>(Ab, Yt, out);
}

// Round 4
// 171.514 us; speedup vs baseline: 1.6641x; 1.6641x over previous
//
#include <hip/hip_runtime.h>
#include <hip/hip_bf16.h>
#include <cstdint>

// Problem constants (B=16, N=4096, D_IN=D_OUT=64)
#define NB   16
#define NN   4096
#define ND   64
#define NJ   1024   // NB*ND columns of the big GEMM

typedef __attribute__((ext_vector_type(8))) short  short8;  // 8 bf16 = 4 VGPRs
typedef __attribute__((ext_vector_type(4))) float  f32x4;

__device__ __forceinline__ unsigned short f2bf(float f) {
  union { float f; unsigned int u; } v; v.f = f;
  unsigned int u = v.u;
  unsigned int r = u + 0x7FFFu + ((u >> 16) & 1u);  // round-to-nearest-even
  return (unsigned short)(r >> 16);
}
__device__ __forceinline__ float bf2f(unsigned short h) {
  union { unsigned int u; float f; } v; v.u = ((unsigned int)h) << 16; return v.f;
}

// ---------------- K1: A fp32 -> bf16, 8 elems/thread, fully vectorized ----------------
__global__ void k_convert(const float* __restrict__ A, unsigned short* __restrict__ Ab) {
  int idx = blockIdx.x * 256 + threadIdx.x;          // 2,097,152 threads exactly
  const float4* p = (const float4*)A + (size_t)idx * 2;
  float4 a = p[0], b = p[1];
  unsigned int w0 = (unsigned int)f2bf(a.x) | ((unsigned int)f2bf(a.y) << 16);
  unsigned int w1 = (unsigned int)f2bf(a.z) | ((unsigned int)f2bf(a.w) << 16);
  unsigned int w2 = (unsigned int)f2bf(b.x) | ((unsigned int)f2bf(b.y) << 16);
  unsigned int w3 = (unsigned int)f2bf(b.z) | ((unsigned int)f2bf(b.w) << 16);
  uint4 o; o.x = w0; o.y = w1; o.z = w2; o.w = w3;
  ((uint4*)Ab)[idx] = o;                             // 16B store
}

// ---------------- K2: Yt[b*64+e][m] = sum_d Z[b][m][d]*W[d][e], fp32 math -> bf16 ----
__global__ void k_zw(const float* __restrict__ Z, const float* __restrict__ W,
                     unsigned short* __restrict__ Yt) {
  int lane = threadIdx.x & 63;
  int e0 = __builtin_amdgcn_readfirstlane((threadIdx.x >> 6) << 4);  // wave-uniform -> s_load W
  int b  = blockIdx.x >> 6;          // [0,16)
  int m0 = (blockIdx.x & 63) << 6;   // [0,4096) step 64
  int m  = m0 + lane;
  const float* zr = Z + ((size_t)b * NN + m) * ND;
  float z[64];
#pragma unroll
  for (int g = 0; g < 16; ++g) *(float4*)&z[g * 4] = ((const float4*)zr)[g];
  float acc[16];
#pragma unroll
  for (int i = 0; i < 16; ++i) acc[i] = 0.f;
#pragma unroll
  for (int d = 0; d < 64; ++d) {
    float zd = z[d];
#pragma unroll
    for (int i = 0; i < 16; ++i) acc[i] += zd * W[d * 64 + e0 + i];  // uniform addr -> SMEM
  }
#pragma unroll
  for (int i = 0; i < 16; ++i)
    Yt[(size_t)(b * 64 + e0 + i) * NN + m] = f2bf(acc[i]);
}

// ---------------- K3: P[kc] += tile of Ab[4096x4096] @ Y (Yt is [j][k]) --------------
// R2's verified core: 128x128 tile, BK=64, 4 waves x (64x64), split-K x4, XOR-swizzled
// LDS (staging-coalesced + conflict-free b128 reads). Epilogue: PLAIN bf16 stores to
// per-kc partial buffers (no atomics, no pre-zeroed out) -> k_reduce sums them.
__device__ __forceinline__ void gl2lds16(const unsigned short* g, unsigned short* l) {
  __builtin_amdgcn_global_load_lds(
      (const __attribute__((address_space(1))) unsigned int*)g,
      (__attribute__((address_space(3))) unsigned int*)l, 16, 0, 0);
}

__launch_bounds__(256, 4)  // 4 blocks/CU: regs ~60V+64A, LDS 4x32K=128K <= 160K
__global__ void k_gemm(const unsigned short* __restrict__ Ab,
                       const unsigned short* __restrict__ Yt,
                       unsigned short* __restrict__ Pb) {
  __shared__ unsigned short lds[16384];  // A tile [0,8192) shorts, B tile [8192,16384): 32 KB
  int tid = threadIdx.x;
  int w = tid >> 6, lane = tid & 63;
  int quad = lane >> 4, l15 = lane & 15;

  // XCD swizzle: bx%8 = XCD. t order: j fastest (8 j-blocks share one A strip in L2),
  // then kc, then m. grid = 8 XCD * 128.
  int x = blockIdx.x & 7;
  int t = blockIdx.x >> 3;           // [0,128)
  int j_blk = t & 7;
  int kc    = (t >> 3) & 3;
  int m_blk = x * 4 + (t >> 5);
  int mrow0 = m_blk * 128;
  int jcol0 = j_blk * 128;
  int kbase = kc * 1024;

  int wrow = (w >> 1) * 64, wcol = (w & 1) * 64;

  // kt-invariant staging offsets: chunk slot s = c0+lane; row = s>>3, kg = (s&7)^(row&7).
  int srcA[4], dst0[4];
#pragma unroll
  for (int i = 0; i < 4; ++i) {
    int c0 = (w * 4 + i) * 64;
    int s  = c0 + lane;
    int row = s >> 3;
    int kg  = (s & 7) ^ (row & 7);
    srcA[i] = row * 4096 + kg * 8;
    dst0[i] = c0 * 8;                // wave-uniform LDS base (shorts)
  }

  // ds_read bases: addr(i,ks) = (row*8 + ((ks*4+quad)^(l15&7)))*8 + (wrow+i*16)*64
  int rbA0 = (wrow + l15) * 64 + ((quad ^ (l15 & 7)) * 8);
  int rbA1 = (wrow + l15) * 64 + (((4 + quad) ^ (l15 & 7)) * 8);
  int rbB0 = 8192 + (wcol + l15) * 64 + ((quad ^ (l15 & 7)) * 8);
  int rbB1 = 8192 + (wcol + l15) * 64 + (((4 + quad) ^ (l15 & 7)) * 8);

  f32x4 acc[4][4];
#pragma unroll
  for (int i = 0; i < 4; ++i)
#pragma unroll
    for (int j = 0; j < 4; ++j) acc[i][j] = (f32x4){0.f, 0.f, 0.f, 0.f};

  for (int kt = 0; kt < 16; ++kt) {
    int k0 = kbase + kt * 64;
    __syncthreads();  // prior iter's LDS reads done before overwrite
#pragma unroll
    for (int i = 0; i < 4; ++i)
      gl2lds16(Ab + (size_t)mrow0 * 4096 + srcA[i] + k0, &lds[dst0[i]]);
#pragma unroll
    for (int i = 0; i < 4; ++i)
      gl2lds16(Yt + (size_t)jcol0 * 4096 + srcA[i] + k0, &lds[8192 + dst0[i]]);
    __syncthreads();  // drains vmcnt (global_load_lds) per barrier semantics
#pragma unroll
    for (int ks = 0; ks < 2; ++ks) {
      int ba = ks ? rbA1 : rbA0;
      int bb = ks ? rbB1 : rbB0;
      short8 af[4], bf[4];
#pragma unroll
      for (int i = 0; i < 4; ++i) {
        af[i] = *(const short8*)&lds[ba + i * 1024];  // +i*16 rows * 64 shorts
        bf[i] = *(const short8*)&lds[bb + i * 1024];
      }
#pragma unroll
      for (int i = 0; i < 4; ++i)
#pragma unroll
        for (int j = 0; j < 4; ++j)
          acc[i][j] = __builtin_amdgcn_mfma_f32_16x16x32_bf16(af[i], bf[j], acc[i][j], 0, 0, 0);
    }
  }

  // Epilogue: C/D layout col=l15, row=quad*4+reg (m89/m91-verified).
  // Plain bf16 stores into P[kc][m][j] (j contiguous): 16-lane x 2B = 32B segments x4.
  unsigned short* P = Pb + (size_t)kc * (NN * NJ);
#pragma unroll
  for (int i = 0; i < 4; ++i) {
    int r0 = mrow0 + wrow + i * 16 + quad * 4;
#pragma unroll
    for (int j = 0; j < 4; ++j) {
      int jc = jcol0 + wcol + j * 16 + l15;
      unsigned short* pp = P + (size_t)r0 * NJ + jc;
#pragma unroll
      for (int rg = 0; rg < 4; ++rg)
        pp[(size_t)rg * NJ] = f2bf(acc[i][j][rg]);
    }
  }
}

// ---------------- K4: out[m-major] = sum_kc P[kc]; 8 floats/thread ------------------
__global__ void k_reduce(const unsigned short* __restrict__ P, float* __restrict__ out) {
  int t = blockIdx.x * 256 + threadIdx.x;      // 524,288 threads exactly
  size_t of = (size_t)t * 8;                   // out flat index (8 consecutive floats)
  int bidx = t >> 15;                          // of >> 18
  int rem  = (int)(of & 262143);               // within one batch: m*64 + e
  int m = rem >> 6, e = rem & 63;
  size_t pj = (size_t)m * NJ + bidx * 64 + e;  // P row-index: [m][j= bidx*64+e]
  float s[8];
#pragma unroll
  for (int u = 0; u < 8; ++u) s[u] = 0.f;
#pragma unroll
  for (int kc = 0; kc < 4; ++kc) {
    short8 v = *(const short8*)(P + (size_t)kc * (NN * NJ) + pj);  // 16B load
#pragma unroll
    for (int u = 0; u < 8; ++u) s[u] += bf2f((unsigned short)v[u]);
  }
  float4 o0 = {s[0], s[1], s[2], s[3]}, o1 = {s[4], s[5], s[6], s[7]};
  ((float4*)(out + of))[0] = o0;
  ((float4*)(out + of))[1] = o1;
}

extern "C" void kernel_launch(void* const* d_in, const int* in_sizes, int n_in,
                              void* d_out, int out_size, void* d_ws, size_t ws_size,
                              hipStream_t stream) {
  const float* Z = (const float*)d_in[0];   // [16][4096][64] fp32
  const float* A = (const float*)d_in[1];   // [4096][4096] fp32
  const float* W = (const float*)d_in[2];   // [64][64] fp32
  float* out = (float*)d_out;               // [16][4096][64] fp32

  unsigned short* Ab = (unsigned short*)d_ws;                                     // 32 MiB bf16 A
  unsigned short* Yt = (unsigned short*)((char*)d_ws + (size_t)32 * 1024 * 1024); // 8 MiB bf16 Y^T
  unsigned short* Pb = (unsigned short*)((char*)d_ws + (size_t)40 * 1024 * 1024); // 32 MiB bf16 partials x4

  k_convert<<<8192, 256, 0, stream>>>(A, Ab);
  k_zw<<<1024, 256, 0, stream>>>(Z, W, Yt);
  k_gemm<<<1024, 256, 0, stream>>>(Ab, Yt, Pb);
  k_reduce<<<2048, 256, 0, stream>>>(Pb, out);
}